// Round 11
// baseline (750.650 us; speedup 1.0000x reference)
//
#include <hip/hip_runtime.h>

#define BN_EPS 1e-3f
#define NREP 16  // BN stat replicas

typedef __attribute__((ext_vector_type(8))) short short8;
typedef __attribute__((ext_vector_type(4))) float float4v;

__device__ __forceinline__ short f2bf(float f) {
    unsigned u = __float_as_uint(f);
    unsigned r = (u + 0x7FFFu + ((u >> 16) & 1u)) >> 16;
    return (short)r;
}

// s_waitcnt vmcnt(N) only (N up to 63: bits [3:0] and [15:14])
template <int N>
__device__ __forceinline__ void waitcnt_vm() {
    __builtin_amdgcn_s_waitcnt(0xF70 | (N & 15) | ((N >> 4) << 14));
}

// ---------------- small utility kernels ----------------

__global__ __launch_bounds__(256) void zero_kernel(float* p, int n) {
    int i = blockIdx.x * 256 + threadIdx.x;
    if (i < n) p[i] = 0.f;
}

__global__ __launch_bounds__(256) void copy_kernel(const float* __restrict__ in,
                                                   float* __restrict__ out, int n) {
    int i = blockIdx.x * 256 + threadIdx.x;
    if (i < n) out[i] = in[i];
}

__global__ __launch_bounds__(256) void zero_rows_kernel(short* a, short* b, long maxN) {
    int t = threadIdx.x;
    if (t < 32) a[maxN * 32 + t] = 0;
    else if (t < 96) a[maxN * 64 + (t - 32)] = 0;
    else if (t < 128) b[maxN * 32 + (t - 96)] = 0;
    else if (t < 192) b[maxN * 64 + (t - 128)] = 0;
}

__global__ __launch_bounds__(256) void xyz_kernel(const int* __restrict__ coords,
                                                  float* __restrict__ out, int N,
                                                  float sx, float sy, float sz) {
    int n = blockIdx.x * 256 + threadIdx.x;
    if (n >= N) return;
    int4 c = ((const int4*)coords)[n];
    out[n * 3 + 0] = c.w * sx;
    out[n * 3 + 1] = c.z * sy - 40.0f;
    out[n * 3 + 2] = c.y * sz - 3.0f;
}

__global__ __launch_bounds__(256) void convert_f0(const float* __restrict__ f,
                                                  short* __restrict__ dst, int N) {
    int i = blockIdx.x * 256 + threadIdx.x;
    if (i >= N * 32) return;
    int c = i & 31, n = i >> 5;
    dst[i] = (c < 4) ? f2bf(f[n * 4 + c]) : (short)0;
}

// ---- weight prep: W [K][CI][CO] fp32 -> Wt [K][c*CT+t][quad][l16][8] bf16 ----
struct PrepAll {
    const float* src[14];
    short* dst[14];
    int CI[14];
    int CO[14];
    int CHP[14];
    int cum[15];
};

__global__ __launch_bounds__(256) void prep_all_kernel(PrepAll d) {
    int i = blockIdx.x * 256 + threadIdx.x;
    if (i >= d.cum[14]) return;
    int l = 0;
    while (l < 13 && i >= d.cum[l + 1]) ++l;
    int f = i - d.cum[l];
    int CO = d.CO[l], CI = d.CI[l];
    int NCH = d.CHP[l] / 32, CT = CO / 16;
    int e = f & 7;
    int u = f >> 3;
    int l16 = u & 15;
    int q = (u >> 4) & 3;
    int u2 = u >> 6;
    int t = u2 % CT;
    int c = (u2 / CT) % NCH;
    int k = u2 / (CT * NCH);
    int ci = c * 32 + q * 8 + e;
    int co = t * 16 + l16;
    float v = (ci < CI) ? d.src[l][((size_t)k * CI + ci) * CO + co] : 0.f;
    d.dst[l][f] = f2bf(v);
}

// per-k A fragments for one wave (32 rows x CHP), held in VGPRs
struct ASet {
    short8 v0, v1, v2, v3;  // (mt0,c0) (mt0,c1) (mt1,c0) (mt1,c1)
};

// ---------------- deep-pipeline wave-independent MFMA sparse conv ----------------
// 256-thread blocks = 4 INDEPENDENT waves (no LDS, no barriers); wave w owns
// rows [(blockIdx*4+w)*32, +32). All operands stream global->VGPR with deep
// software pipelines to maximize outstanding requests (the R2..R10 44us
// invariance was latency-bound starvation: ~10 outstanding/wave vs 400-900cy
// memory latency; R10 additionally exposed full B latency every tap).
//   B: 2-ahead (3 live BSets)   A: 3-ahead (4 live ASets)   rb: 5-ahead
// Issue at iter i: B(i+2), rb(i+5) | WAIT | A(i+3) (uses rb(i+3)) | MFMA(i).
// Steady wait = 2*(BF+A)+4 outstanding; exact tail regimes below. Dead taps
// skip MFMA via ballot on landed rb. launch_bounds(256,2): 256-VGPR cap, no
// spill at ~150-220 live regs (R8 lesson: never undersize the cap).
template <int CHP, int CO, int K>
__global__ __launch_bounds__(256, 2) void sconv_dp(const short* __restrict__ feat,
                                                   const int* __restrict__ rb,
                                                   const short* __restrict__ Wt,
                                                   float* __restrict__ out,
                                                   float* __restrict__ stats, int N, int zrow) {
    constexpr int NCH = CHP / 32;
    constexpr int CT = CO / 16;
    constexpr int BTILE = CO * CHP;      // shorts
    constexpr int BF = BTILE / 512;      // B loads per tile (1KB coalesced each)
    constexpr int A_ = 2 * NCH;          // A gather loads per tile
    constexpr int WS = 2 * (A_ + BF) + 4;  // steady-state allowed outstanding
    constexpr int WM = 2 * (A_ + BF) + 2;
    constexpr int W2 = 2 * (A_ + BF);
    constexpr int W1 = A_ + BF;

    const int tid = threadIdx.x;
    const int w = tid >> 6;
    const int lane = tid & 63;
    const int quad = lane >> 4;
    const int l16 = lane & 15;
    const int tile = blockIdx.x * 4 + w;
    const int m0 = tile * 32;

    const short* fquad = feat + quad * 8;

    // per-lane rb row pointers (clamped; OOB rows forced to -1 after load)
    const int r0 = m0 + l16;
    const int r1 = r0 + 16;
    const bool v0 = r0 < N;
    const bool v1 = r1 < N;
    const int* p0 = rb + (v0 ? r0 : 0);
    const int* p1 = rb + (v1 ? r1 : 0);

    auto loadRb = [&](int k) {
        int2 j;
        j.x = p0[(size_t)k * N];
        j.y = p1[(size_t)k * N];
        if (!v0) j.x = -1;
        if (!v1) j.y = -1;
        return j;
    };
    auto aliveOf = [&](int2 j) {
        return (__ballot(j.x >= 0) | __ballot(j.y >= 0)) != 0ull;
    };

    struct BSet {
        short8 f[BF];
    };
    auto loadB = [&](int k) {
        BSet b;
        const short* wk = Wt + (size_t)k * BTILE;
#pragma unroll
        for (int j = 0; j < BF; ++j)
            b.f[j] = *(const short8*)(wk + ((j * 64) + quad * 16 + l16) * 8);
        return b;
    };
    auto issueA = [&](int2 j) {
        ASet s;
        const short* q0 = fquad + (size_t)(j.x < 0 ? zrow : j.x) * CHP;
        const short* q1 = fquad + (size_t)(j.y < 0 ? zrow : j.y) * CHP;
        s.v0 = *(const short8*)q0;
        s.v2 = *(const short8*)q1;
        if constexpr (NCH == 2) {
            s.v1 = *(const short8*)(q0 + 32);
            s.v3 = *(const short8*)(q1 + 32);
        } else {
            s.v1 = (short8)0;
            s.v3 = (short8)0;
        }
        return s;
    };

    float4v acc[2][CT];
#pragma unroll
    for (int mt = 0; mt < 2; ++mt)
#pragma unroll
        for (int t = 0; t < CT; ++t) acc[mt][t] = (float4v)0.f;

    // ---- prologue: rb(0..2), drain; B(0),A(0),B(1),A(1),A(2); rb(3),rb(4) ----
    int2 t0 = loadRb(0);
    int2 t1, t2;
    t1.x = t1.y = t2.x = t2.y = -1;
    if (K > 1) t1 = loadRb(1);
    if (K > 2) t2 = loadRb(2);
    waitcnt_vm<0>();
    bool alA = aliveOf(t0);
    bool alB = (K > 1) ? aliveOf(t1) : false;
    bool alC = (K > 2) ? aliveOf(t2) : false;
    bool alD = false;

    BSet bA = loadB(0), bB, bC;
    ASet sA = issueA(t0), sB, sC, sD;
    if (K > 1) {
        bB = loadB(1);
        sB = issueA(t1);
    }
    if (K > 2) sC = issueA(t2);
    int2 qA, qB, qC;
    qA.x = qA.y = qB.x = qB.y = qC.x = qC.y = -1;
    if (K > 3) qA = loadRb(3);
    if (K > 4) qB = loadRb(4);

#pragma unroll 1
    for (int i = 0; i < K; ++i) {
        if (i + 2 < K) bC = loadB(i + 2);
        if (i + 5 < K) qC = loadRb(i + 5);
        const int d = K - 1 - i;
        if (d >= 5) waitcnt_vm<WS>();
        else if (d == 4) waitcnt_vm<WM>();
        else if (d >= 2) waitcnt_vm<W2>();
        else if (d == 1) waitcnt_vm<W1>();
        else waitcnt_vm<0>();
        if (i + 3 < K) {
            alD = aliveOf(qA);  // qA = rb(i+3), landed by the wait
            sD = issueA(qA);
        } else {
            alD = false;
        }
        if (alA) {
#pragma unroll
            for (int c = 0; c < NCH; ++c) {
#pragma unroll
                for (int t = 0; t < CT; ++t) {
                    short8 bf = bA.f[c * CT + t];
#pragma unroll
                    for (int mt = 0; mt < 2; ++mt) {
                        short8 af = (mt == 0) ? ((c == 0) ? sA.v0 : sA.v1)
                                              : ((c == 0) ? sA.v2 : sA.v3);
                        acc[mt][t] =
                            __builtin_amdgcn_mfma_f32_16x16x32_bf16(af, bf, acc[mt][t], 0, 0, 0);
                    }
                }
            }
        }
        bA = bB;
        bB = bC;
        sA = sB;
        sB = sC;
        sC = sD;
        alA = alB;
        alB = alC;
        alC = alD;
        qA = qB;
        qB = qC;
    }

    // stores: D layout col = lane&15, row = quad*4 + reg. Plain (cached) stores.
#pragma unroll
    for (int mt = 0; mt < 2; ++mt)
#pragma unroll
        for (int t = 0; t < CT; ++t) {
            int col = t * 16 + l16;
#pragma unroll
            for (int r = 0; r < 4; ++r) {
                int orow = m0 + mt * 16 + quad * 4 + r;
                if (orow < N) out[(size_t)orow * CO + col] = acc[mt][t][r];
            }
        }

    // per-wave BN stats -> replica atomics (no LDS: shfl reduce over quads).
    // (OOB rows and -1 gathers hit the zero row, so their acc entries are 0)
    float* st = stats + (size_t)(tile & (NREP - 1)) * 128;
#pragma unroll
    for (int t = 0; t < CT; ++t) {
        float s = 0.f, ss = 0.f;
#pragma unroll
        for (int mt = 0; mt < 2; ++mt)
#pragma unroll
            for (int r = 0; r < 4; ++r) {
                float v = acc[mt][t][r];
                s += v;
                ss += v * v;
            }
        s += __shfl_xor(s, 16);
        s += __shfl_xor(s, 32);
        ss += __shfl_xor(ss, 16);
        ss += __shfl_xor(ss, 32);
        if (lane < 16) {
            atomicAdd(&st[t * 16 + lane], s);
            atomicAdd(&st[64 + t * 16 + lane], ss);
        }
    }
}

// ---------------- BN apply + ReLU, 8-wide vectorized ----------------
template <int COUT, int CHPN, bool F32OUT, bool BFOUT>
__global__ __launch_bounds__(256) void bn_apply(const float* __restrict__ x,
                                                const float* __restrict__ stats,
                                                const float* __restrict__ g,
                                                const float* __restrict__ b,
                                                float* __restrict__ fout,
                                                short* __restrict__ bfout, int N) {
    constexpr int CW = BFOUT ? CHPN : COUT;
    constexpr int CV = CW / 8;  // short8/float8 groups per row
    __shared__ float ssc[COUT];
    __shared__ float ssh[COUT];
    int tid = threadIdx.x;
    if (tid < COUT) {
        float s = 0.f, q = 0.f;
#pragma unroll
        for (int r = 0; r < NREP; ++r) {
            s += stats[r * 128 + tid];
            q += stats[r * 128 + 64 + tid];
        }
        float inv = 1.0f / (float)N;
        float m = s * inv;
        float v = q * inv - m * m;
        float sc = g[tid] / sqrtf(v + BN_EPS);
        ssc[tid] = sc;
        ssh[tid] = b[tid] - m * sc;
    }
    __syncthreads();
    long i = (long)blockIdx.x * 256 + tid;
    if (i >= (long)N * CV) return;
    int c8 = (int)(i % CV);
    long n = i / CV;
    int cb = c8 * 8;
    float y[8];
#pragma unroll
    for (int j = 0; j < 8; ++j) y[j] = 0.f;
    if (cb < COUT) {
        const float4v* xr = (const float4v*)(x + n * COUT + cb);
        float4v a0 = xr[0];
        float4v a1 = xr[1];
#pragma unroll
        for (int j = 0; j < 4; ++j) {
            y[j] = fmaxf(a0[j] * ssc[cb + j] + ssh[cb + j], 0.f);
            y[4 + j] = fmaxf(a1[j] * ssc[cb + 4 + j] + ssh[cb + 4 + j], 0.f);
        }
        if constexpr (F32OUT) {
            float* fo = fout + n * COUT + cb;
            if ((((unsigned long long)fout) & 15ull) == 0) {  // uniform branch
                float4v o0, o1;
#pragma unroll
                for (int j = 0; j < 4; ++j) {
                    o0[j] = y[j];
                    o1[j] = y[4 + j];
                }
                ((float4v*)fo)[0] = o0;
                ((float4v*)fo)[1] = o1;
            } else {
#pragma unroll
                for (int j = 0; j < 8; ++j) fo[j] = y[j];
            }
        }
    }
    if constexpr (BFOUT) {
        short8 p;
#pragma unroll
        for (int j = 0; j < 8; ++j) p[j] = f2bf(y[j]);
        *(short8*)(bfout + n * CHPN + cb) = p;
    }
}

// ---------------- host helpers ----------------

template <int CHP, int CO, int K>
static void conv(const short* fin, const int* rb, const short* wt, float* preact, float* stats,
                 int N, int zrow, hipStream_t stream) {
    dim3 grid((N + 127) / 128);
    hipLaunchKernelGGL((sconv_dp<CHP, CO, K>), grid, dim3(256), 0, stream, fin, rb, wt, preact,
                       stats, N, zrow);
}

template <int COUT, int CHPN, bool F32OUT, bool BFOUT>
static void apply(const float* preact, const float* stats, const float* g, const float* b,
                  float* fout, short* bfout, int N, hipStream_t stream) {
    constexpr int CW = BFOUT ? CHPN : COUT;
    constexpr int CV = CW / 8;
    int blocks = (int)(((long)N * CV + 255) / 256);
    hipLaunchKernelGGL((bn_apply<COUT, CHPN, F32OUT, BFOUT>), dim3(blocks), dim3(256), 0, stream,
                       preact, stats, g, b, fout, bfout, N);
}

extern "C" void kernel_launch(void* const* d_in, const int* in_sizes, int n_in, void* d_out,
                              int out_size, void* d_ws, size_t ws_size, hipStream_t stream) {
    const float* features = (const float*)d_in[0];
    const float* W[14];
    const float* G[14];
    const float* Bb[14];
    for (int i = 0; i < 14; ++i) {
        W[i] = (const float*)d_in[1 + 3 * i];
        G[i] = (const float*)d_in[2 + 3 * i];
        Bb[i] = (const float*)d_in[3 + 3 * i];
    }
    const int* coords0 = (const int*)d_in[43];
    const int* coords1 = (const int*)d_in[44];
    const int* coords2 = (const int*)d_in[45];
    const int* coords3 = (const int*)d_in[46];
    const int* rb0 = (const int*)d_in[47];
    const int* rbc1 = (const int*)d_in[48];
    const int* rb1 = (const int*)d_in[49];
    const int* rbc2 = (const int*)d_in[50];
    const int* rb2 = (const int*)d_in[51];
    const int* rbc3 = (const int*)d_in[52];
    const int* rb3 = (const int*)d_in[53];
    const int* rbc4 = (const int*)d_in[54];

    const int N0 = in_sizes[0] / 4;
    const int N1 = in_sizes[44] / 4;
    const int N2 = in_sizes[45] / 4;
    const int N3 = in_sizes[46] / 4;
    const int N4 = in_sizes[54] / 3;

    float* out = (float*)d_out;
    long off = 0;
    float* xyz0 = out + off; off += (long)N0 * 3;
    float* f0   = out + off; off += (long)N0 * 4;
    float* xyz1 = out + off; off += (long)N1 * 3;
    float* f1   = out + off; off += (long)N1 * 32;
    float* xyz2 = out + off; off += (long)N2 * 3;
    float* f2   = out + off; off += (long)N2 * 64;
    float* xyz3 = out + off; off += (long)N3 * 3;
    float* f3   = out + off; off += (long)N3 * 64;
    float* f4   = out + off;

    long maxN = N0;
    if (N1 > maxN) maxN = N1;
    if (N2 > maxN) maxN = N2;
    if (N3 > maxN) maxN = N3;
    if (N4 > maxN) maxN = N4;
    const int zrow = (int)maxN;

    float* preact = (float*)d_ws;                         // maxN*64 fp32
    float* statsBase = preact + (size_t)maxN * 64;        // 14 * NREP * 128 fp32
    short* bfA = (short*)(statsBase + 14 * NREP * 128);   // (maxN+1)*64 bf16
    short* bfB = bfA + (size_t)(maxN + 1) * 64;           // (maxN+1)*64 bf16
    short* wtBase = bfB + (size_t)(maxN + 1) * 64;        // swizzled bf16 weights

    static const int KK[14] = {27, 27, 27, 27, 27, 27, 27, 27, 27, 27, 27, 27, 27, 3};
    static const int CI[14] = {4, 16, 16, 32, 32, 32, 64, 64, 64, 64, 64, 64, 64, 64};
    static const int CO[14] = {16, 16, 32, 32, 32, 64, 64, 64, 64, 64, 64, 64, 64, 64};
    short* WT[14];
    PrepAll pd;
    {
        size_t o = 0;
        int cum = 0;
        for (int l = 0; l < 14; ++l) {
            WT[l] = wtBase + o;
            int chp = CI[l] <= 32 ? 32 : 64;
            pd.src[l] = W[l];
            pd.dst[l] = WT[l];
            pd.CI[l] = CI[l];
            pd.CO[l] = CO[l];
            pd.CHP[l] = chp;
            pd.cum[l] = cum;
            cum += KK[l] * CO[l] * chp;
            o += (size_t)KK[l] * CO[l] * chp;
        }
        pd.cum[14] = cum;
    }

    int nstats = 14 * NREP * 128;
    hipLaunchKernelGGL(zero_kernel, dim3((nstats + 255) / 256), dim3(256), 0, stream, statsBase,
                       nstats);
    hipLaunchKernelGGL(zero_rows_kernel, dim3(1), dim3(256), 0, stream, bfA, bfB, maxN);
    hipLaunchKernelGGL(prep_all_kernel, dim3((pd.cum[14] + 255) / 256), dim3(256), 0, stream, pd);

    hipLaunchKernelGGL(copy_kernel, dim3((N0 * 4 + 255) / 256), dim3(256), 0, stream, features, f0,
                       N0 * 4);
    hipLaunchKernelGGL(xyz_kernel, dim3((N0 + 255) / 256), dim3(256), 0, stream, coords0, xyz0, N0,
                       0.05f, 0.05f, 0.1f);
    hipLaunchKernelGGL(xyz_kernel, dim3((N1 + 255) / 256), dim3(256), 0, stream, coords1, xyz1, N1,
                       0.1f, 0.1f, 0.2f);
    hipLaunchKernelGGL(xyz_kernel, dim3((N2 + 255) / 256), dim3(256), 0, stream, coords2, xyz2, N2,
                       0.2f, 0.2f, 0.4f);
    hipLaunchKernelGGL(xyz_kernel, dim3((N3 + 255) / 256), dim3(256), 0, stream, coords3, xyz3, N3,
                       0.4f, 0.4f, 0.8f);
    hipLaunchKernelGGL(convert_f0, dim3((N0 * 32 + 255) / 256), dim3(256), 0, stream, features,
                       bfA, N0);

    float* st = statsBase;
#define STAT(l) (st + (size_t)(l)*NREP * 128)

    conv<32, 16, 27>(bfA, rb0, WT[0], preact, STAT(0), N0, zrow, stream);
    apply<16, 32, false, true>(preact, STAT(0), G[0], Bb[0], nullptr, bfB, N0, stream);
    conv<32, 16, 27>(bfB, rb0, WT[1], preact, STAT(1), N0, zrow, stream);
    apply<16, 32, false, true>(preact, STAT(1), G[1], Bb[1], nullptr, bfA, N0, stream);
    conv<32, 32, 27>(bfA, rbc1, WT[2], preact, STAT(2), N1, zrow, stream);
    apply<32, 32, true, true>(preact, STAT(2), G[2], Bb[2], f1, bfB, N1, stream);

    conv<32, 32, 27>(bfB, rb1, WT[3], preact, STAT(3), N1, zrow, stream);
    apply<32, 32, false, true>(preact, STAT(3), G[3], Bb[3], nullptr, bfA, N1, stream);
    conv<32, 32, 27>(bfA, rb1, WT[4], preact, STAT(4), N1, zrow, stream);
    apply<32, 32, false, true>(preact, STAT(4), G[4], Bb[4], nullptr, bfB, N1, stream);
    conv<32, 64, 27>(bfB, rbc2, WT[5], preact, STAT(5), N2, zrow, stream);
    apply<64, 64, true, true>(preact, STAT(5), G[5], Bb[5], f2, bfA, N2, stream);

    conv<64, 64, 27>(bfA, rb2, WT[6], preact, STAT(6), N2, zrow, stream);
    apply<64, 64, false, true>(preact, STAT(6), G[6], Bb[6], nullptr, bfB, N2, stream);
    conv<64, 64, 27>(bfB, rb2, WT[7], preact, STAT(7), N2, zrow, stream);
    apply<64, 64, false, true>(preact, STAT(7), G[7], Bb[7], nullptr, bfA, N2, stream);
    conv<64, 64, 27>(bfA, rb2, WT[8], preact, STAT(8), N2, zrow, stream);
    apply<64, 64, false, true>(preact, STAT(8), G[8], Bb[8], nullptr, bfB, N2, stream);
    conv<64, 64, 27>(bfB, rbc3, WT[9], preact, STAT(9), N3, zrow, stream);
    apply<64, 64, true, true>(preact, STAT(9), G[9], Bb[9], f3, bfA, N3, stream);

    conv<64, 64, 27>(bfA, rb3, WT[10], preact, STAT(10), N3, zrow, stream);
    apply<64, 64, false, true>(preact, STAT(10), G[10], Bb[10], nullptr, bfB, N3, stream);
    conv<64, 64, 27>(bfB, rb3, WT[11], preact, STAT(11), N3, zrow, stream);
    apply<64, 64, false, true>(preact, STAT(11), G[11], Bb[11], nullptr, bfA, N3, stream);
    conv<64, 64, 27>(bfA, rb3, WT[12], preact, STAT(12), N3, zrow, stream);
    apply<64, 64, false, true>(preact, STAT(12), G[12], Bb[12], nullptr, bfB, N3, stream);
    conv<64, 64, 3>(bfB, rbc4, WT[13], preact, STAT(13), N4, zrow, stream);
    apply<64, 64, true, false>(preact, STAT(13), G[13], Bb[13], f4, nullptr, N4, stream);
#undef STAT
}

// Round 12
// 748.530 us; speedup vs baseline: 1.0028x; 1.0028x over previous
//
#include <hip/hip_runtime.h>

#define BN_EPS 1e-3f
#define NREP 16  // BN stat replicas

typedef __attribute__((ext_vector_type(8))) short short8;
typedef __attribute__((ext_vector_type(4))) float float4v;

__device__ __forceinline__ short f2bf(float f) {
    unsigned u = __float_as_uint(f);
    unsigned r = (u + 0x7FFFu + ((u >> 16) & 1u)) >> 16;
    return (short)r;
}

// s_waitcnt vmcnt(N) only (N up to 63: bits [3:0] and [15:14])
template <int N>
__device__ __forceinline__ void waitcnt_vm() {
    __builtin_amdgcn_s_waitcnt(0xF70 | (N & 15) | ((N >> 4) << 14));
}

// raw s_barrier (no compiler vmcnt(0) drain; we wait explicitly)
__device__ __forceinline__ void wave_barrier() { asm volatile("s_barrier" ::: "memory"); }

// async global -> LDS, 16B/lane; lds dst wave-uniform base + lane*16
__device__ __forceinline__ void dma16(const short* g, short* l) {
    __builtin_amdgcn_global_load_lds((const __attribute__((address_space(1))) void*)g,
                                     (__attribute__((address_space(3))) void*)l, 16, 0, 0);
}

// ---------------- small utility kernels ----------------

__global__ __launch_bounds__(256) void zero_kernel(float* p, int n) {
    int i = blockIdx.x * 256 + threadIdx.x;
    if (i < n) p[i] = 0.f;
}

__global__ __launch_bounds__(256) void copy_kernel(const float* __restrict__ in,
                                                   float* __restrict__ out, int n) {
    int i = blockIdx.x * 256 + threadIdx.x;
    if (i < n) out[i] = in[i];
}

__global__ __launch_bounds__(256) void zero_rows_kernel(short* a, short* b, long maxN) {
    int t = threadIdx.x;
    if (t < 32) a[maxN * 32 + t] = 0;
    else if (t < 96) a[maxN * 64 + (t - 32)] = 0;
    else if (t < 128) b[maxN * 32 + (t - 96)] = 0;
    else if (t < 192) b[maxN * 64 + (t - 128)] = 0;
}

__global__ __launch_bounds__(256) void xyz_kernel(const int* __restrict__ coords,
                                                  float* __restrict__ out, int N,
                                                  float sx, float sy, float sz) {
    int n = blockIdx.x * 256 + threadIdx.x;
    if (n >= N) return;
    int4 c = ((const int4*)coords)[n];
    out[n * 3 + 0] = c.w * sx;
    out[n * 3 + 1] = c.z * sy - 40.0f;
    out[n * 3 + 2] = c.y * sz - 3.0f;
}

__global__ __launch_bounds__(256) void convert_f0(const float* __restrict__ f,
                                                  short* __restrict__ dst, int N) {
    int i = blockIdx.x * 256 + threadIdx.x;
    if (i >= N * 32) return;
    int c = i & 31, n = i >> 5;
    dst[i] = (c < 4) ? f2bf(f[n * 4 + c]) : (short)0;
}

// ---- weight prep: W [K][CI][CO] fp32 -> Wt [K][c*CT+t][quad][l16][8] bf16 ----
struct PrepAll {
    const float* src[14];
    short* dst[14];
    int CI[14];
    int CO[14];
    int CHP[14];
    int cum[15];
};

__global__ __launch_bounds__(256) void prep_all_kernel(PrepAll d) {
    int i = blockIdx.x * 256 + threadIdx.x;
    if (i >= d.cum[14]) return;
    int l = 0;
    while (l < 13 && i >= d.cum[l + 1]) ++l;
    int f = i - d.cum[l];
    int CO = d.CO[l], CI = d.CI[l];
    int NCH = d.CHP[l] / 32, CT = CO / 16;
    int e = f & 7;
    int u = f >> 3;
    int l16 = u & 15;
    int q = (u >> 4) & 3;
    int u2 = u >> 6;
    int t = u2 % CT;
    int c = (u2 / CT) % NCH;
    int k = u2 / (CT * NCH);
    int ci = c * 32 + q * 8 + e;
    int co = t * 16 + l16;
    float v = (ci < CI) ? d.src[l][((size_t)k * CI + ci) * CO + co] : 0.f;
    d.dst[l][f] = f2bf(v);
}

// per-k A fragments for one wave (32 rows x CHP), held in VGPRs
struct ASet {
    short8 v0, v1, v2, v3;  // (mt0,c0) (mt0,c1) (mt1,c0) (mt1,c1)
};

// ---------------- deep-ring hybrid MFMA sparse conv ----------------
// R2 skeleton (4 waves x 32 rows, sIdx LDS staging + active-k compaction,
// B via global_load_lds ring) with pipeline depth bought in LDS, not VGPRs:
//   B ring: 6 slots, issued 5 taps ahead (depth paid in LDS -> free VGPRs)
//   A gathers: 3 taps ahead (4 ASets)
//   per-tap wait: counted vmcnt (never drain mid-loop) allowing ~2 iters of
//   A + ~3 loop-issued B shares outstanding across the barrier.
// Rationale: R2..R11 all pinned at ~44us because outstanding-bytes/CU (~4KB)
// << BW*latency (~17KB); VGPR-paid depth (R11) collapsed occupancy. LDS-paid
// depth raises outstanding ~5x at unchanged occupancy.
// Per-iter order: issueA(i+3) | WAIT | barrier | issueB(i+5) | compute(i).
// Wait constants: newer-than-A(i) = min(d,3)*A + B(i+2..i+4) loop-issues,
// where d = nk-1-i; for i<3 the B terms came from the prologue (OLDER than
// A(i)) so the safe constant is A-only (over-wait, never under-wait).
template <int CHP, int CO, int K>
__global__ __launch_bounds__(256, 3) void sconv_hyb(const short* __restrict__ feat,
                                                    const int* __restrict__ rb,
                                                    const short* __restrict__ Wt,
                                                    float* __restrict__ out,
                                                    float* __restrict__ stats, int N, int zrow) {
    constexpr int NCH = CHP / 32;
    constexpr int CT = CO / 16;
    constexpr int BTILE = CO * CHP;  // shorts
    constexpr int NB = BTILE / 512;  // B DMA insts per tile (1KB each)
    constexpr int A_ = 2 * NCH;      // A gather loads per wave per tile
    constexpr int ROWS = 128;
    constexpr int SLOTS = 6;

    __shared__ __align__(16) short ldsB[SLOTS * BTILE];
    __shared__ int sIdx[K * ROWS];
    __shared__ int sFlag[K];
    __shared__ int sKl[K];
    __shared__ int sKn;

    const int tid = threadIdx.x;
    const int w = tid >> 6;
    const int lane = tid & 63;
    const int quad = lane >> 4;
    const int l16 = lane & 15;
    const int m0 = blockIdx.x * ROWS;

    if (tid < K) sFlag[tid] = 0;
    __syncthreads();
    for (int e = tid; e < K * ROWS; e += 256) {
        int r = m0 + (e & (ROWS - 1));
        int v = (r < N) ? rb[(size_t)(e >> 7) * N + r] : -1;
        sIdx[e] = v;
        if (v >= 0) sFlag[e >> 7] = 1;  // benign race: same value
    }
    __syncthreads();
    // wave 0: compact active k list via ballot + prefix popcount
    if (w == 0) {
        int f = (lane < K) ? sFlag[lane] : 0;
        unsigned long long m = __ballot(f != 0);
        if (f) sKl[__popcll(m & ((1ull << lane) - 1ull))] = lane;
        if (lane == 0) sKn = (int)__popcll(m);
    }
    __syncthreads();
    const int nk = sKn;

    const short* fquad = feat + quad * 8;

    auto issueB = [&](int kp, int slot) {
        const short* wk = Wt + (size_t)kp * BTILE + lane * 8;
        short* bb = ldsB + slot * BTILE;
#pragma unroll
        for (int jj = 0; jj < (NB + 3) / 4; ++jj) {
            int j = jj * 4 + w;
            if (j < NB) dma16(wk + j * 512, bb + j * 512);
        }
    };
    auto issueA = [&](int kp) {
        ASet s;
        int i0 = sIdx[kp * ROWS + w * 32 + l16];
        int i1 = sIdx[kp * ROWS + w * 32 + 16 + l16];
        const short* p0 = fquad + (size_t)(i0 < 0 ? zrow : i0) * CHP;
        const short* p1 = fquad + (size_t)(i1 < 0 ? zrow : i1) * CHP;
        s.v0 = *(const short8*)p0;
        s.v2 = *(const short8*)p1;
        if constexpr (NCH == 2) {
            s.v1 = *(const short8*)(p0 + 32);
            s.v3 = *(const short8*)(p1 + 32);
        } else {
            s.v1 = (short8)0;
            s.v3 = (short8)0;
        }
        return s;
    };

    float4v acc[2][CT];
#pragma unroll
    for (int mt = 0; mt < 2; ++mt)
#pragma unroll
        for (int t = 0; t < CT; ++t) acc[mt][t] = (float4v)0.f;

    // per-wave B share counts
    constexpr int BW0 = NB / 4 + ((NB % 4) > 0 ? 1 : 0);
    constexpr int BW1 = NB / 4 + ((NB % 4) > 1 ? 1 : 0);
    constexpr int BW2 = NB / 4 + ((NB % 4) > 2 ? 1 : 0);
    constexpr int BW3 = NB / 4;

#define WAITW(AT, BT)                                        \
    do {                                                     \
        if (w == 0) waitcnt_vm<(AT)*A_ + (BT)*BW0>();        \
        else if (w == 1) waitcnt_vm<(AT)*A_ + (BT)*BW1>();   \
        else if (w == 2) waitcnt_vm<(AT)*A_ + (BT)*BW2>();   \
        else waitcnt_vm<(AT)*A_ + (BT)*BW3>();               \
    } while (0)

    // ---- prologue: B(0..4) into slots 0..4, A(0..2) ----
    ASet sA{}, sB{}, sC{}, sD{};
#pragma unroll
    for (int s = 0; s < 5; ++s)
        if (s < nk) issueB(sKl[s], s);
    if (nk > 0) sA = issueA(sKl[0]);
    if (nk > 1) sB = issueA(sKl[1]);
    if (nk > 2) sC = issueA(sKl[2]);

    int slotRd = 0, slotWr = 5;
#pragma unroll 1
    for (int i = 0; i < nk; ++i) {
        if (i + 3 < nk) sD = issueA(sKl[i + 3]);
        const int d = nk - 1 - i;
        if (i >= 3) {
            if (d >= 4) WAITW(3, 3);
            else if (d == 3) WAITW(3, 2);
            else if (d == 2) WAITW(2, 1);
            else if (d == 1) WAITW(1, 0);
            else WAITW(0, 0);
        } else {
            // prologue-issued B's are OLDER than A(i): A-only constants are
            // the safe (conservative) bound here.
            if (d >= 3) WAITW(3, 0);
            else if (d == 2) WAITW(2, 0);
            else if (d == 1) WAITW(1, 0);
            else WAITW(0, 0);
        }
        __builtin_amdgcn_sched_barrier(0);
        wave_barrier();  // all waves: B(i) landed, done reading slot of tap i-1
        if (i + 5 < nk) {
            issueB(sKl[i + 5], slotWr);
            slotWr = (slotWr == SLOTS - 1) ? 0 : slotWr + 1;
        }
        // compute tap i: B from LDS slot, A from sA registers
        const short* bb = ldsB + slotRd * BTILE;
#pragma unroll
        for (int c = 0; c < NCH; ++c) {
#pragma unroll
            for (int t = 0; t < CT; ++t) {
                short8 bf = *(const short8*)(bb + ((c * CT + t) * 64 + quad * 16 + l16) * 8);
#pragma unroll
                for (int mt = 0; mt < 2; ++mt) {
                    short8 af = (mt == 0) ? ((c == 0) ? sA.v0 : sA.v1)
                                          : ((c == 0) ? sA.v2 : sA.v3);
                    acc[mt][t] = __builtin_amdgcn_mfma_f32_16x16x32_bf16(af, bf, acc[mt][t], 0,
                                                                         0, 0);
                }
            }
        }
        sA = sB;
        sB = sC;
        sC = sD;
        slotRd = (slotRd == SLOTS - 1) ? 0 : slotRd + 1;
    }
#undef WAITW

    // stores: D layout col = lane&15, row = quad*4 + reg. Plain (cached) stores.
#pragma unroll
    for (int mt = 0; mt < 2; ++mt)
#pragma unroll
        for (int t = 0; t < CT; ++t) {
            int col = t * 16 + l16;
#pragma unroll
            for (int r = 0; r < 4; ++r) {
                int orow = m0 + w * 32 + mt * 16 + quad * 4 + r;
                if (orow < N) out[(size_t)orow * CO + col] = acc[mt][t][r];
            }
        }

    // block-level BN stats -> one atomic per channel per block.
    // (OOB rows and -1 gathers hit the zero row, so their acc entries are 0)
    __syncthreads();
    float* red = (float*)ldsB;  // [4][2*CO]
#pragma unroll
    for (int t = 0; t < CT; ++t) {
        float s = 0.f, ss = 0.f;
#pragma unroll
        for (int mt = 0; mt < 2; ++mt)
#pragma unroll
            for (int r = 0; r < 4; ++r) {
                float v = acc[mt][t][r];
                s += v;
                ss += v * v;
            }
        s += __shfl_xor(s, 16);
        s += __shfl_xor(s, 32);
        ss += __shfl_xor(ss, 16);
        ss += __shfl_xor(ss, 32);
        if (lane < 16) {
            red[w * 2 * CO + t * 16 + lane] = s;
            red[w * 2 * CO + CO + t * 16 + lane] = ss;
        }
    }
    __syncthreads();
    if (tid < 2 * CO) {
        float v = red[tid] + red[2 * CO + tid] + red[4 * CO + tid] + red[6 * CO + tid];
        float* st = stats + (size_t)(blockIdx.x & (NREP - 1)) * 128;
        atomicAdd(&st[(tid < CO) ? tid : (64 + tid - CO)], v);
    }
}

// ---------------- BN apply + ReLU, 8-wide vectorized ----------------
template <int COUT, int CHPN, bool F32OUT, bool BFOUT>
__global__ __launch_bounds__(256) void bn_apply(const float* __restrict__ x,
                                                const float* __restrict__ stats,
                                                const float* __restrict__ g,
                                                const float* __restrict__ b,
                                                float* __restrict__ fout,
                                                short* __restrict__ bfout, int N) {
    constexpr int CW = BFOUT ? CHPN : COUT;
    constexpr int CV = CW / 8;  // short8/float8 groups per row
    __shared__ float ssc[COUT];
    __shared__ float ssh[COUT];
    int tid = threadIdx.x;
    if (tid < COUT) {
        float s = 0.f, q = 0.f;
#pragma unroll
        for (int r = 0; r < NREP; ++r) {
            s += stats[r * 128 + tid];
            q += stats[r * 128 + 64 + tid];
        }
        float inv = 1.0f / (float)N;
        float m = s * inv;
        float v = q * inv - m * m;
        float sc = g[tid] / sqrtf(v + BN_EPS);
        ssc[tid] = sc;
        ssh[tid] = b[tid] - m * sc;
    }
    __syncthreads();
    long i = (long)blockIdx.x * 256 + tid;
    if (i >= (long)N * CV) return;
    int c8 = (int)(i % CV);
    long n = i / CV;
    int cb = c8 * 8;
    float y[8];
#pragma unroll
    for (int j = 0; j < 8; ++j) y[j] = 0.f;
    if (cb < COUT) {
        const float4v* xr = (const float4v*)(x + n * COUT + cb);
        float4v a0 = xr[0];
        float4v a1 = xr[1];
#pragma unroll
        for (int j = 0; j < 4; ++j) {
            y[j] = fmaxf(a0[j] * ssc[cb + j] + ssh[cb + j], 0.f);
            y[4 + j] = fmaxf(a1[j] * ssc[cb + 4 + j] + ssh[cb + 4 + j], 0.f);
        }
        if constexpr (F32OUT) {
            float* fo = fout + n * COUT + cb;
            if ((((unsigned long long)fout) & 15ull) == 0) {  // uniform branch
                float4v o0, o1;
#pragma unroll
                for (int j = 0; j < 4; ++j) {
                    o0[j] = y[j];
                    o1[j] = y[4 + j];
                }
                ((float4v*)fo)[0] = o0;
                ((float4v*)fo)[1] = o1;
            } else {
#pragma unroll
                for (int j = 0; j < 8; ++j) fo[j] = y[j];
            }
        }
    }
    if constexpr (BFOUT) {
        short8 p;
#pragma unroll
        for (int j = 0; j < 8; ++j) p[j] = f2bf(y[j]);
        *(short8*)(bfout + n * CHPN + cb) = p;
    }
}

// ---------------- host helpers ----------------

template <int CHP, int CO, int K>
static void conv(const short* fin, const int* rb, const short* wt, float* preact, float* stats,
                 int N, int zrow, hipStream_t stream) {
    dim3 grid((N + 127) / 128);
    hipLaunchKernelGGL((sconv_hyb<CHP, CO, K>), grid, dim3(256), 0, stream, fin, rb, wt, preact,
                       stats, N, zrow);
}

template <int COUT, int CHPN, bool F32OUT, bool BFOUT>
static void apply(const float* preact, const float* stats, const float* g, const float* b,
                  float* fout, short* bfout, int N, hipStream_t stream) {
    constexpr int CW = BFOUT ? CHPN : COUT;
    constexpr int CV = CW / 8;
    int blocks = (int)(((long)N * CV + 255) / 256);
    hipLaunchKernelGGL((bn_apply<COUT, CHPN, F32OUT, BFOUT>), dim3(blocks), dim3(256), 0, stream,
                       preact, stats, g, b, fout, bfout, N);
}

extern "C" void kernel_launch(void* const* d_in, const int* in_sizes, int n_in, void* d_out,
                              int out_size, void* d_ws, size_t ws_size, hipStream_t stream) {
    const float* features = (const float*)d_in[0];
    const float* W[14];
    const float* G[14];
    const float* Bb[14];
    for (int i = 0; i < 14; ++i) {
        W[i] = (const float*)d_in[1 + 3 * i];
        G[i] = (const float*)d_in[2 + 3 * i];
        Bb[i] = (const float*)d_in[3 + 3 * i];
    }
    const int* coords0 = (const int*)d_in[43];
    const int* coords1 = (const int*)d_in[44];
    const int* coords2 = (const int*)d_in[45];
    const int* coords3 = (const int*)d_in[46];
    const int* rb0 = (const int*)d_in[47];
    const int* rbc1 = (const int*)d_in[48];
    const int* rb1 = (const int*)d_in[49];
    const int* rbc2 = (const int*)d_in[50];
    const int* rb2 = (const int*)d_in[51];
    const int* rbc3 = (const int*)d_in[52];
    const int* rb3 = (const int*)d_in[53];
    const int* rbc4 = (const int*)d_in[54];

    const int N0 = in_sizes[0] / 4;
    const int N1 = in_sizes[44] / 4;
    const int N2 = in_sizes[45] / 4;
    const int N3 = in_sizes[46] / 4;
    const int N4 = in_sizes[54] / 3;

    float* out = (float*)d_out;
    long off = 0;
    float* xyz0 = out + off; off += (long)N0 * 3;
    float* f0   = out + off; off += (long)N0 * 4;
    float* xyz1 = out + off; off += (long)N1 * 3;
    float* f1   = out + off; off += (long)N1 * 32;
    float* xyz2 = out + off; off += (long)N2 * 3;
    float* f2   = out + off; off += (long)N2 * 64;
    float* xyz3 = out + off; off += (long)N3 * 3;
    float* f3   = out + off; off += (long)N3 * 64;
    float* f4   = out + off;

    long maxN = N0;
    if (N1 > maxN) maxN = N1;
    if (N2 > maxN) maxN = N2;
    if (N3 > maxN) maxN = N3;
    if (N4 > maxN) maxN = N4;
    const int zrow = (int)maxN;

    float* preact = (float*)d_ws;                         // maxN*64 fp32
    float* statsBase = preact + (size_t)maxN * 64;        // 14 * NREP * 128 fp32
    short* bfA = (short*)(statsBase + 14 * NREP * 128);   // (maxN+1)*64 bf16
    short* bfB = bfA + (size_t)(maxN + 1) * 64;           // (maxN+1)*64 bf16
    short* wtBase = bfB + (size_t)(maxN + 1) * 64;        // swizzled bf16 weights

    static const int KK[14] = {27, 27, 27, 27, 27, 27, 27, 27, 27, 27, 27, 27, 27, 3};
    static const int CI[14] = {4, 16, 16, 32, 32, 32, 64, 64, 64, 64, 64, 64, 64, 64};
    static const int CO[14] = {16, 16, 32, 32, 32, 64, 64, 64, 64, 64, 64, 64, 64, 64};
    short* WT[14];
    PrepAll pd;
    {
        size_t o = 0;
        int cum = 0;
        for (int l = 0; l < 14; ++l) {
            WT[l] = wtBase + o;
            int chp = CI[l] <= 32 ? 32 : 64;
            pd.src[l] = W[l];
            pd.dst[l] = WT[l];
            pd.CI[l] = CI[l];
            pd.CO[l] = CO[l];
            pd.CHP[l] = chp;
            pd.cum[l] = cum;
            cum += KK[l] * CO[l] * chp;
            o += (size_t)KK[l] * CO[l] * chp;
        }
        pd.cum[14] = cum;
    }

    int nstats = 14 * NREP * 128;
    hipLaunchKernelGGL(zero_kernel, dim3((nstats + 255) / 256), dim3(256), 0, stream, statsBase,
                       nstats);
    hipLaunchKernelGGL(zero_rows_kernel, dim3(1), dim3(256), 0, stream, bfA, bfB, maxN);
    hipLaunchKernelGGL(prep_all_kernel, dim3((pd.cum[14] + 255) / 256), dim3(256), 0, stream, pd);

    hipLaunchKernelGGL(copy_kernel, dim3((N0 * 4 + 255) / 256), dim3(256), 0, stream, features, f0,
                       N0 * 4);
    hipLaunchKernelGGL(xyz_kernel, dim3((N0 + 255) / 256), dim3(256), 0, stream, coords0, xyz0, N0,
                       0.05f, 0.05f, 0.1f);
    hipLaunchKernelGGL(xyz_kernel, dim3((N1 + 255) / 256), dim3(256), 0, stream, coords1, xyz1, N1,
                       0.1f, 0.1f, 0.2f);
    hipLaunchKernelGGL(xyz_kernel, dim3((N2 + 255) / 256), dim3(256), 0, stream, coords2, xyz2, N2,
                       0.2f, 0.2f, 0.4f);
    hipLaunchKernelGGL(xyz_kernel, dim3((N3 + 255) / 256), dim3(256), 0, stream, coords3, xyz3, N3,
                       0.4f, 0.4f, 0.8f);
    hipLaunchKernelGGL(convert_f0, dim3((N0 * 32 + 255) / 256), dim3(256), 0, stream, features,
                       bfA, N0);

    float* st = statsBase;
#define STAT(l) (st + (size_t)(l)*NREP * 128)

    conv<32, 16, 27>(bfA, rb0, WT[0], preact, STAT(0), N0, zrow, stream);
    apply<16, 32, false, true>(preact, STAT(0), G[0], Bb[0], nullptr, bfB, N0, stream);
    conv<32, 16, 27>(bfB, rb0, WT[1], preact, STAT(1), N0, zrow, stream);
    apply<16, 32, false, true>(preact, STAT(1), G[1], Bb[1], nullptr, bfA, N0, stream);
    conv<32, 32, 27>(bfA, rbc1, WT[2], preact, STAT(2), N1, zrow, stream);
    apply<32, 32, true, true>(preact, STAT(2), G[2], Bb[2], f1, bfB, N1, stream);

    conv<32, 32, 27>(bfB, rb1, WT[3], preact, STAT(3), N1, zrow, stream);
    apply<32, 32, false, true>(preact, STAT(3), G[3], Bb[3], nullptr, bfA, N1, stream);
    conv<32, 32, 27>(bfA, rb1, WT[4], preact, STAT(4), N1, zrow, stream);
    apply<32, 32, false, true>(preact, STAT(4), G[4], Bb[4], nullptr, bfB, N1, stream);
    conv<32, 64, 27>(bfB, rbc2, WT[5], preact, STAT(5), N2, zrow, stream);
    apply<64, 64, true, true>(preact, STAT(5), G[5], Bb[5], f2, bfA, N2, stream);

    conv<64, 64, 27>(bfA, rb2, WT[6], preact, STAT(6), N2, zrow, stream);
    apply<64, 64, false, true>(preact, STAT(6), G[6], Bb[6], nullptr, bfB, N2, stream);
    conv<64, 64, 27>(bfB, rb2, WT[7], preact, STAT(7), N2, zrow, stream);
    apply<64, 64, false, true>(preact, STAT(7), G[7], Bb[7], nullptr, bfA, N2, stream);
    conv<64, 64, 27>(bfA, rb2, WT[8], preact, STAT(8), N2, zrow, stream);
    apply<64, 64, false, true>(preact, STAT(8), G[8], Bb[8], nullptr, bfB, N2, stream);
    conv<64, 64, 27>(bfB, rbc3, WT[9], preact, STAT(9), N3, zrow, stream);
    apply<64, 64, true, true>(preact, STAT(9), G[9], Bb[9], f3, bfA, N3, stream);

    conv<64, 64, 27>(bfA, rb3, WT[10], preact, STAT(10), N3, zrow, stream);
    apply<64, 64, false, true>(preact, STAT(10), G[10], Bb[10], nullptr, bfB, N3, stream);
    conv<64, 64, 27>(bfB, rb3, WT[11], preact, STAT(11), N3, zrow, stream);
    apply<64, 64, false, true>(preact, STAT(11), G[11], Bb[11], nullptr, bfA, N3, stream);
    conv<64, 64, 27>(bfA, rb3, WT[12], preact, STAT(12), N3, zrow, stream);
    apply<64, 64, false, true>(preact, STAT(12), G[12], Bb[12], nullptr, bfB, N3, stream);
    conv<64, 64, 3>(bfB, rbc4, WT[13], preact, STAT(13), N4, zrow, stream);
    apply<64, 64, true, false>(preact, STAT(13), G[13], Bb[13], f4, nullptr, N4, stream);
#undef STAT
}

// Round 13
// 649.642 us; speedup vs baseline: 1.1555x; 1.1522x over previous
//
#include <hip/hip_runtime.h>

#define BN_EPS 1e-3f
#define NREP 16  // BN stat replicas

typedef __attribute__((ext_vector_type(8))) short short8;
typedef __attribute__((ext_vector_type(4))) float float4v;

__device__ __forceinline__ short f2bf(float f) {
    unsigned u = __float_as_uint(f);
    unsigned r = (u + 0x7FFFu + ((u >> 16) & 1u)) >> 16;
    return (short)r;
}

__device__ __forceinline__ float bf2f(short s) {
    return __uint_as_float(((unsigned)(unsigned short)s) << 16);
}

// s_waitcnt vmcnt(N) only (N up to 63: bits [3:0] and [15:14])
template <int N>
__device__ __forceinline__ void waitcnt_vm() {
    __builtin_amdgcn_s_waitcnt(0xF70 | (N & 15) | ((N >> 4) << 14));
}

// ---------------- small utility kernels ----------------

__global__ __launch_bounds__(256) void zero_kernel(float* p, int n) {
    int i = blockIdx.x * 256 + threadIdx.x;
    if (i < n) p[i] = 0.f;
}

__global__ __launch_bounds__(256) void copy_kernel(const float* __restrict__ in,
                                                   float* __restrict__ out, int n) {
    int i = blockIdx.x * 256 + threadIdx.x;
    if (i < n) out[i] = in[i];
}

__global__ __launch_bounds__(256) void zero_rows_kernel(short* a, short* b, long maxN) {
    int t = threadIdx.x;
    if (t < 32) a[maxN * 32 + t] = 0;
    else if (t < 96) a[maxN * 64 + (t - 32)] = 0;
    else if (t < 128) b[maxN * 32 + (t - 96)] = 0;
    else if (t < 192) b[maxN * 64 + (t - 128)] = 0;
}

__global__ __launch_bounds__(256) void xyz_kernel(const int* __restrict__ coords,
                                                  float* __restrict__ out, int N,
                                                  float sx, float sy, float sz) {
    int n = blockIdx.x * 256 + threadIdx.x;
    if (n >= N) return;
    int4 c = ((const int4*)coords)[n];
    out[n * 3 + 0] = c.w * sx;
    out[n * 3 + 1] = c.z * sy - 40.0f;
    out[n * 3 + 2] = c.y * sz - 3.0f;
}

__global__ __launch_bounds__(256) void convert_f0(const float* __restrict__ f,
                                                  short* __restrict__ dst, int N) {
    int i = blockIdx.x * 256 + threadIdx.x;
    if (i >= N * 32) return;
    int c = i & 31, n = i >> 5;
    dst[i] = (c < 4) ? f2bf(f[n * 4 + c]) : (short)0;
}

// ---- weight prep: W [K][CI][CO] fp32 -> Wt [K][c*CT+t][quad][l16][8] bf16 ----
struct PrepAll {
    const float* src[14];
    short* dst[14];
    int CI[14];
    int CO[14];
    int CHP[14];
    int cum[15];
};

__global__ __launch_bounds__(256) void prep_all_kernel(PrepAll d) {
    int i = blockIdx.x * 256 + threadIdx.x;
    if (i >= d.cum[14]) return;
    int l = 0;
    while (l < 13 && i >= d.cum[l + 1]) ++l;
    int f = i - d.cum[l];
    int CO = d.CO[l], CI = d.CI[l];
    int NCH = d.CHP[l] / 32, CT = CO / 16;
    int e = f & 7;
    int u = f >> 3;
    int l16 = u & 15;
    int q = (u >> 4) & 3;
    int u2 = u >> 6;
    int t = u2 % CT;
    int c = (u2 / CT) % NCH;
    int k = u2 / (CT * NCH);
    int ci = c * 32 + q * 8 + e;
    int co = t * 16 + l16;
    float v = (ci < CI) ? d.src[l][((size_t)k * CI + ci) * CO + co] : 0.f;
    d.dst[l][f] = f2bf(v);
}

// per-k A fragments for one wave (32 rows x CHP), held in VGPRs
struct ASet {
    short8 v0, v1, v2, v3;  // (mt0,c0) (mt0,c1) (mt1,c0) (mt1,c1)
};

// ---------- wave-compacted MFMA sparse conv (R10 base + per-wave tap skip) ----------
// 64-thread (1-wave) blocks, 32 output rows each. Phase 1: stage this wave's
// rb slice [K][32] into LDS (3.5KB), flag alive taps, ballot-compact the list.
// Phase 2: R10-style register pipeline over ONLY the alive taps:
//   B: global->VGPR, DB-ahead (DB=2, or 1 when BF=8 to protect VGPRs)
//   A: gathers 2-ahead; counted vmcnt per tail regime d=nk-1-i (never drain).
// Rationale: at 32-row granularity most taps are completely dead for subm
// layers (~15/27 at layer-3 density, 26/27 at layer-0) but R2..R12 paid full
// per-tap cost (loads+wait+loop) for them; block-level (128-row) compaction
// couldn't see this. Issue order per iter: B(i+DB), A(i+2) | WAIT | MFMA(i).
// Prologue interleaved B0,A0,[B1],A1 so steady wait constants hold at i=0.
// Preact is stored bf16 (halves conv WRITE + bn read; eps ~0.1 << 2.33 thr).
template <int CHP, int CO, int K>
__global__ __launch_bounds__(64, 2) void sconv_wc(const short* __restrict__ feat,
                                                  const int* __restrict__ rb,
                                                  const short* __restrict__ Wt,
                                                  short* __restrict__ out,
                                                  float* __restrict__ stats, int N, int zrow) {
    constexpr int NCH = CHP / 32;
    constexpr int CT = CO / 16;
    constexpr int BTILE = CO * CHP;  // shorts
    constexpr int BF = BTILE / 512;  // B loads per tile (1KB coalesced each)
    constexpr int A_ = 2 * NCH;      // A gather loads per tile
    constexpr int DB = (BF >= 8) ? 1 : 2;
    // wait constants (count of loads issued after the last-needed one)
    constexpr int WN2 = 2 * (BF + A_);  // DB=2, d>=2
    constexpr int WN1 = BF + A_;        // DB=2, d==1
    constexpr int WD2 = 2 * A_ + BF;    // DB=1, d>=2
    constexpr int WD1 = A_ + BF;        // DB=1, d==1

    __shared__ int sIdx[K * 32];
    __shared__ int sFlag[K];
    __shared__ int sKl[K];
    __shared__ int sKn;

    const int lane = threadIdx.x & 63;
    const int quad = lane >> 4;
    const int l16 = lane & 15;
    const int m0 = blockIdx.x * 32;

    if (lane < K) sFlag[lane] = 0;
    __syncthreads();
    for (int e = lane; e < K * 32; e += 64) {
        int r = m0 + (e & 31);
        int v = (r < N) ? rb[(size_t)(e >> 5) * N + r] : -1;
        sIdx[e] = v;
        if (v >= 0) sFlag[e >> 5] = 1;  // benign race: same value
    }
    __syncthreads();
    {
        int f = (lane < K) ? sFlag[lane] : 0;
        unsigned long long m = __ballot(f != 0);
        if (f) sKl[__popcll(m & ((1ull << lane) - 1ull))] = lane;
        if (lane == 0) sKn = (int)__popcll(m);
    }
    __syncthreads();
    const int nk = sKn;

    const short* fquad = feat + quad * 8;

    struct BSet {
        short8 f[BF];
    };
    auto issueB = [&](int kp) {
        BSet b;
        const short* wk = Wt + (size_t)kp * BTILE;
#pragma unroll
        for (int j = 0; j < BF; ++j)
            b.f[j] = *(const short8*)(wk + ((j * 64) + quad * 16 + l16) * 8);
        return b;
    };
    auto issueA = [&](int kp) {
        ASet s;
        int i0 = sIdx[kp * 32 + l16];
        int i1 = sIdx[kp * 32 + 16 + l16];
        const short* q0 = fquad + (size_t)(i0 < 0 ? zrow : i0) * CHP;
        const short* q1 = fquad + (size_t)(i1 < 0 ? zrow : i1) * CHP;
        s.v0 = *(const short8*)q0;
        s.v2 = *(const short8*)q1;
        if constexpr (NCH == 2) {
            s.v1 = *(const short8*)(q0 + 32);
            s.v3 = *(const short8*)(q1 + 32);
        } else {
            s.v1 = (short8)0;
            s.v3 = (short8)0;
        }
        return s;
    };

    float4v acc[2][CT];
#pragma unroll
    for (int mt = 0; mt < 2; ++mt)
#pragma unroll
        for (int t = 0; t < CT; ++t) acc[mt][t] = (float4v)0.f;

    // ---- prologue (interleaved so steady wait constants hold from i=0) ----
    BSet bA{}, bB{}, bC{};
    ASet sA{}, sB{}, sC{};
    if (nk > 0) {
        bA = issueB(sKl[0]);
        sA = issueA(sKl[0]);
    }
    if (DB == 2 && nk > 1) bB = issueB(sKl[1]);
    if (nk > 1) sB = issueA(sKl[1]);

#pragma unroll 1
    for (int i = 0; i < nk; ++i) {
        if constexpr (DB == 2) {
            if (i + 2 < nk) bC = issueB(sKl[i + 2]);
        } else {
            if (i + 1 < nk) bB = issueB(sKl[i + 1]);
        }
        if (i + 2 < nk) sC = issueA(sKl[i + 2]);
        const int d = nk - 1 - i;
        if constexpr (DB == 2) {
            if (d >= 2) waitcnt_vm<WN2>();
            else if (d == 1) waitcnt_vm<WN1>();
            else waitcnt_vm<0>();
        } else {
            if (d >= 2) waitcnt_vm<WD2>();
            else if (d == 1) waitcnt_vm<WD1>();
            else waitcnt_vm<0>();
        }
#pragma unroll
        for (int c = 0; c < NCH; ++c) {
#pragma unroll
            for (int t = 0; t < CT; ++t) {
                short8 bf = bA.f[c * CT + t];
#pragma unroll
                for (int mt = 0; mt < 2; ++mt) {
                    short8 af = (mt == 0) ? ((c == 0) ? sA.v0 : sA.v1)
                                          : ((c == 0) ? sA.v2 : sA.v3);
                    acc[mt][t] =
                        __builtin_amdgcn_mfma_f32_16x16x32_bf16(af, bf, acc[mt][t], 0, 0, 0);
                }
            }
        }
        if constexpr (DB == 2) {
            bA = bB;
            bB = bC;
        } else {
            bA = bB;
        }
        sA = sB;
        sB = sC;
    }

    // stores: D layout col = lane&15, row = quad*4 + reg. bf16 preact.
#pragma unroll
    for (int mt = 0; mt < 2; ++mt)
#pragma unroll
        for (int t = 0; t < CT; ++t) {
            int col = t * 16 + l16;
#pragma unroll
            for (int r = 0; r < 4; ++r) {
                int orow = m0 + mt * 16 + quad * 4 + r;
                if (orow < N) out[(size_t)orow * CO + col] = f2bf(acc[mt][t][r]);
            }
        }

    // per-wave BN stats (fp32 acc) -> replica atomics.
    // (OOB rows and -1 gathers hit the zero row, so their acc entries are 0)
    float* st = stats + (size_t)(blockIdx.x & (NREP - 1)) * 128;
#pragma unroll
    for (int t = 0; t < CT; ++t) {
        float s = 0.f, ss = 0.f;
#pragma unroll
        for (int mt = 0; mt < 2; ++mt)
#pragma unroll
            for (int r = 0; r < 4; ++r) {
                float v = acc[mt][t][r];
                s += v;
                ss += v * v;
            }
        s += __shfl_xor(s, 16);
        s += __shfl_xor(s, 32);
        ss += __shfl_xor(ss, 16);
        ss += __shfl_xor(ss, 32);
        if (lane < 16) {
            atomicAdd(&st[t * 16 + lane], s);
            atomicAdd(&st[64 + t * 16 + lane], ss);
        }
    }
}

// ---------------- BN apply + ReLU, 8-wide vectorized (bf16 preact in) ------------
template <int COUT, int CHPN, bool F32OUT, bool BFOUT>
__global__ __launch_bounds__(256) void bn_apply(const short* __restrict__ x,
                                                const float* __restrict__ stats,
                                                const float* __restrict__ g,
                                                const float* __restrict__ b,
                                                float* __restrict__ fout,
                                                short* __restrict__ bfout, int N) {
    constexpr int CW = BFOUT ? CHPN : COUT;
    constexpr int CV = CW / 8;  // 8-channel groups per row
    __shared__ float ssc[COUT];
    __shared__ float ssh[COUT];
    int tid = threadIdx.x;
    if (tid < COUT) {
        float s = 0.f, q = 0.f;
#pragma unroll
        for (int r = 0; r < NREP; ++r) {
            s += stats[r * 128 + tid];
            q += stats[r * 128 + 64 + tid];
        }
        float inv = 1.0f / (float)N;
        float m = s * inv;
        float v = q * inv - m * m;
        float sc = g[tid] / sqrtf(v + BN_EPS);
        ssc[tid] = sc;
        ssh[tid] = b[tid] - m * sc;
    }
    __syncthreads();
    long i = (long)blockIdx.x * 256 + tid;
    if (i >= (long)N * CV) return;
    int c8 = (int)(i % CV);
    long n = i / CV;
    int cb = c8 * 8;
    float y[8];
#pragma unroll
    for (int j = 0; j < 8; ++j) y[j] = 0.f;
    if (cb < COUT) {
        short8 xv = *(const short8*)(x + n * COUT + cb);
#pragma unroll
        for (int j = 0; j < 8; ++j)
            y[j] = fmaxf(bf2f(xv[j]) * ssc[cb + j] + ssh[cb + j], 0.f);
        if constexpr (F32OUT) {
            float* fo = fout + n * COUT + cb;
            if ((((unsigned long long)fout) & 15ull) == 0) {  // uniform branch
                float4v o0, o1;
#pragma unroll
                for (int j = 0; j < 4; ++j) {
                    o0[j] = y[j];
                    o1[j] = y[4 + j];
                }
                ((float4v*)fo)[0] = o0;
                ((float4v*)fo)[1] = o1;
            } else {
#pragma unroll
                for (int j = 0; j < 8; ++j) fo[j] = y[j];
            }
        }
    }
    if constexpr (BFOUT) {
        short8 p;
#pragma unroll
        for (int j = 0; j < 8; ++j) p[j] = f2bf(y[j]);
        *(short8*)(bfout + n * CHPN + cb) = p;
    }
}

// ---------------- host helpers ----------------

template <int CHP, int CO, int K>
static void conv(const short* fin, const int* rb, const short* wt, short* preact, float* stats,
                 int N, int zrow, hipStream_t stream) {
    dim3 grid((N + 31) / 32);
    hipLaunchKernelGGL((sconv_wc<CHP, CO, K>), grid, dim3(64), 0, stream, fin, rb, wt, preact,
                       stats, N, zrow);
}

template <int COUT, int CHPN, bool F32OUT, bool BFOUT>
static void apply(const short* preact, const float* stats, const float* g, const float* b,
                  float* fout, short* bfout, int N, hipStream_t stream) {
    constexpr int CW = BFOUT ? CHPN : COUT;
    constexpr int CV = CW / 8;
    int blocks = (int)(((long)N * CV + 255) / 256);
    hipLaunchKernelGGL((bn_apply<COUT, CHPN, F32OUT, BFOUT>), dim3(blocks), dim3(256), 0, stream,
                       preact, stats, g, b, fout, bfout, N);
}

extern "C" void kernel_launch(void* const* d_in, const int* in_sizes, int n_in, void* d_out,
                              int out_size, void* d_ws, size_t ws_size, hipStream_t stream) {
    const float* features = (const float*)d_in[0];
    const float* W[14];
    const float* G[14];
    const float* Bb[14];
    for (int i = 0; i < 14; ++i) {
        W[i] = (const float*)d_in[1 + 3 * i];
        G[i] = (const float*)d_in[2 + 3 * i];
        Bb[i] = (const float*)d_in[3 + 3 * i];
    }
    const int* coords0 = (const int*)d_in[43];
    const int* coords1 = (const int*)d_in[44];
    const int* coords2 = (const int*)d_in[45];
    const int* coords3 = (const int*)d_in[46];
    const int* rb0 = (const int*)d_in[47];
    const int* rbc1 = (const int*)d_in[48];
    const int* rb1 = (const int*)d_in[49];
    const int* rbc2 = (const int*)d_in[50];
    const int* rb2 = (const int*)d_in[51];
    const int* rbc3 = (const int*)d_in[52];
    const int* rb3 = (const int*)d_in[53];
    const int* rbc4 = (const int*)d_in[54];

    const int N0 = in_sizes[0] / 4;
    const int N1 = in_sizes[44] / 4;
    const int N2 = in_sizes[45] / 4;
    const int N3 = in_sizes[46] / 4;
    const int N4 = in_sizes[54] / 3;

    float* out = (float*)d_out;
    long off = 0;
    float* xyz0 = out + off; off += (long)N0 * 3;
    float* f0   = out + off; off += (long)N0 * 4;
    float* xyz1 = out + off; off += (long)N1 * 3;
    float* f1   = out + off; off += (long)N1 * 32;
    float* xyz2 = out + off; off += (long)N2 * 3;
    float* f2   = out + off; off += (long)N2 * 64;
    float* xyz3 = out + off; off += (long)N3 * 3;
    float* f3   = out + off; off += (long)N3 * 64;
    float* f4   = out + off;

    long maxN = N0;
    if (N1 > maxN) maxN = N1;
    if (N2 > maxN) maxN = N2;
    if (N3 > maxN) maxN = N3;
    if (N4 > maxN) maxN = N4;
    const int zrow = (int)maxN;

    short* preact = (short*)d_ws;                         // maxN*64 bf16
    float* statsBase = (float*)(preact + (size_t)maxN * 64);  // 14 * NREP * 128 fp32
    short* bfA = (short*)(statsBase + 14 * NREP * 128);   // (maxN+1)*64 bf16
    short* bfB = bfA + (size_t)(maxN + 1) * 64;           // (maxN+1)*64 bf16
    short* wtBase = bfB + (size_t)(maxN + 1) * 64;        // swizzled bf16 weights

    static const int KK[14] = {27, 27, 27, 27, 27, 27, 27, 27, 27, 27, 27, 27, 27, 3};
    static const int CI[14] = {4, 16, 16, 32, 32, 32, 64, 64, 64, 64, 64, 64, 64, 64};
    static const int CO[14] = {16, 16, 32, 32, 32, 64, 64, 64, 64, 64, 64, 64, 64, 64};
    short* WT[14];
    PrepAll pd;
    {
        size_t o = 0;
        int cum = 0;
        for (int l = 0; l < 14; ++l) {
            WT[l] = wtBase + o;
            int chp = CI[l] <= 32 ? 32 : 64;
            pd.src[l] = W[l];
            pd.dst[l] = WT[l];
            pd.CI[l] = CI[l];
            pd.CO[l] = CO[l];
            pd.CHP[l] = chp;
            pd.cum[l] = cum;
            cum += KK[l] * CO[l] * chp;
            o += (size_t)KK[l] * CO[l] * chp;
        }
        pd.cum[14] = cum;
    }

    int nstats = 14 * NREP * 128;
    hipLaunchKernelGGL(zero_kernel, dim3((nstats + 255) / 256), dim3(256), 0, stream, statsBase,
                       nstats);
    hipLaunchKernelGGL(zero_rows_kernel, dim3(1), dim3(256), 0, stream, bfA, bfB, maxN);
    hipLaunchKernelGGL(prep_all_kernel, dim3((pd.cum[14] + 255) / 256), dim3(256), 0, stream, pd);

    hipLaunchKernelGGL(copy_kernel, dim3((N0 * 4 + 255) / 256), dim3(256), 0, stream, features, f0,
                       N0 * 4);
    hipLaunchKernelGGL(xyz_kernel, dim3((N0 + 255) / 256), dim3(256), 0, stream, coords0, xyz0, N0,
                       0.05f, 0.05f, 0.1f);
    hipLaunchKernelGGL(xyz_kernel, dim3((N1 + 255) / 256), dim3(256), 0, stream, coords1, xyz1, N1,
                       0.1f, 0.1f, 0.2f);
    hipLaunchKernelGGL(xyz_kernel, dim3((N2 + 255) / 256), dim3(256), 0, stream, coords2, xyz2, N2,
                       0.2f, 0.2f, 0.4f);
    hipLaunchKernelGGL(xyz_kernel, dim3((N3 + 255) / 256), dim3(256), 0, stream, coords3, xyz3, N3,
                       0.4f, 0.4f, 0.8f);
    hipLaunchKernelGGL(convert_f0, dim3((N0 * 32 + 255) / 256), dim3(256), 0, stream, features,
                       bfA, N0);

    float* st = statsBase;
#define STAT(l) (st + (size_t)(l)*NREP * 128)

    conv<32, 16, 27>(bfA, rb0, WT[0], preact, STAT(0), N0, zrow, stream);
    apply<16, 32, false, true>(preact, STAT(0), G[0], Bb[0], nullptr, bfB, N0, stream);
    conv<32, 16, 27>(bfB, rb0, WT[1], preact, STAT(1), N0, zrow, stream);
    apply<16, 32, false, true>(preact, STAT(1), G[1], Bb[1], nullptr, bfA, N0, stream);
    conv<32, 32, 27>(bfA, rbc1, WT[2], preact, STAT(2), N1, zrow, stream);
    apply<32, 32, true, true>(preact, STAT(2), G[2], Bb[2], f1, bfB, N1, stream);

    conv<32, 32, 27>(bfB, rb1, WT[3], preact, STAT(3), N1, zrow, stream);
    apply<32, 32, false, true>(preact, STAT(3), G[3], Bb[3], nullptr, bfA, N1, stream);
    conv<32, 32, 27>(bfA, rb1, WT[4], preact, STAT(4), N1, zrow, stream);
    apply<32, 32, false, true>(preact, STAT(4), G[4], Bb[4], nullptr, bfB, N1, stream);
    conv<32, 64, 27>(bfB, rbc2, WT[5], preact, STAT(5), N2, zrow, stream);
    apply<64, 64, true, true>(preact, STAT(5), G[5], Bb[5], f2, bfA, N2, stream);

    conv<64, 64, 27>(bfA, rb2, WT[6], preact, STAT(6), N2, zrow, stream);
    apply<64, 64, false, true>(preact, STAT(6), G[6], Bb[6], nullptr, bfB, N2, stream);
    conv<64, 64, 27>(bfB, rb2, WT[7], preact, STAT(7), N2, zrow, stream);
    apply<64, 64, false, true>(preact, STAT(7), G[7], Bb[7], nullptr, bfA, N2, stream);
    conv<64, 64, 27>(bfA, rb2, WT[8], preact, STAT(8), N2, zrow, stream);
    apply<64, 64, false, true>(preact, STAT(8), G[8], Bb[8], nullptr, bfB, N2, stream);
    conv<64, 64, 27>(bfB, rbc3, WT[9], preact, STAT(9), N3, zrow, stream);
    apply<64, 64, true, true>(preact, STAT(9), G[9], Bb[9], f3, bfA, N3, stream);

    conv<64, 64, 27>(bfA, rb3, WT[10], preact, STAT(10), N3, zrow, stream);
    apply<64, 64, false, true>(preact, STAT(10), G[10], Bb[10], nullptr, bfB, N3, stream);
    conv<64, 64, 27>(bfB, rb3, WT[11], preact, STAT(11), N3, zrow, stream);
    apply<64, 64, false, true>(preact, STAT(11), G[11], Bb[11], nullptr, bfA, N3, stream);
    conv<64, 64, 27>(bfA, rb3, WT[12], preact, STAT(12), N3, zrow, stream);
    apply<64, 64, false, true>(preact, STAT(12), G[12], Bb[12], nullptr, bfB, N3, stream);
    conv<64, 64, 3>(bfB, rbc4, WT[13], preact, STAT(13), N4, zrow, stream);
    apply<64, 64, true, false>(preact, STAT(13), G[13], Bb[13], f4, nullptr, N4, stream);
#undef STAT
}